// Round 2
// baseline (536.749 us; speedup 1.0000x reference)
//
#include <hip/hip_runtime.h>
#include <math.h>

#define NN 20000
#define NE 320000
#define NF (NN*64)
#define TB 16

// ---------------- weight transpose ----------------
__global__ __launch_bounds__(256) void k_transpose_res(
    const float* __restrict__ Ws, const float* __restrict__ Wv,
    float* __restrict__ Wst, float* __restrict__ Wvt)
{
  int i = blockIdx.x*256 + threadIdx.x;   // 0..40959
  int spec = i >> 12;
  int g = (i >> 6) & 63;
  int f = i & 63;
  Wst[spec*4096 + f*64 + g] = Ws[i];
  Wvt[spec*4096 + f*64 + g] = Wv[i];
}

// ---------------- counting sort of edges by receiver ----------------
__global__ __launch_bounds__(256) void k_hist_rank(const int* __restrict__ receivers,
                                                   int* __restrict__ count,
                                                   int* __restrict__ rank)
{
  int e = blockIdx.x*256 + threadIdx.x;
  rank[e] = atomicAdd(&count[receivers[e]], 1);
}

__global__ __launch_bounds__(256) void k_scan(const int* __restrict__ count,
                                              int* __restrict__ offset)
{
  __shared__ int part[256];
  int t = threadIdx.x;
  const int PER = 79;                     // 256*79 = 20224 >= NN
  int s = 0;
  for(int i=0;i<PER;++i){ int idx = t*PER+i; if(idx < NN) s += count[idx]; }
  part[t] = s;
  __syncthreads();
  for(int off=1; off<256; off<<=1){
    int v = (t>=off) ? part[t-off] : 0;
    __syncthreads();
    part[t] += v;
    __syncthreads();
  }
  int run = t ? part[t-1] : 0;
  for(int i=0;i<PER;++i){
    int idx = t*PER+i;
    if(idx < NN){ offset[idx] = run; run += count[idx]; }
  }
  if(t==255) offset[NN] = run;
}

// Scatter edge data into receiver-sorted arrays (coalesced reads, scattered writes).
// Also normalizes the edge vector once here.
__global__ __launch_bounds__(256) void k_scatter(
    const int* __restrict__ senders, const int* __restrict__ receivers,
    const float* __restrict__ vectors, const float* __restrict__ radial,
    const int* __restrict__ offset, const int* __restrict__ rank,
    int* __restrict__ srt_snd, int* __restrict__ srt_rcv,
    float* __restrict__ srt_y, float* __restrict__ srt_rad)
{
  int e = blockIdx.x*256 + threadIdx.x;
  int r = receivers[e];
  int slot = offset[r] + rank[e];
  srt_snd[slot] = senders[e];
  srt_rcv[slot] = r;
  float vx = vectors[e*3], vy = vectors[e*3+1], vz = vectors[e*3+2];
  float rinv = rsqrtf(vx*vx + vy*vy + vz*vz + 1e-12f);
  float4 y4; y4.x = vx*rinv; y4.y = vy*rinv; y4.z = vz*rinv; y4.w = 0.f;
  *(float4*)(srt_y + (size_t)slot*4) = y4;
  float4 ra = *(const float4*)(radial + (size_t)e*8);
  float4 rb = *(const float4*)(radial + (size_t)e*8 + 4);
  *(float4*)(srt_rad + (size_t)slot*8)     = ra;
  *(float4*)(srt_rad + (size_t)slot*8 + 4) = rb;
}

// ---------------- node pre-pass: 4 nodes per wave ----------------
// h layout: h[(n*64+lane)*4 + c], c in {s, vx, vy, vz}  (float4 per lane)
__global__ __launch_bounds__(256) void k_node_pre(
    const float* __restrict__ node_feats, const float* __restrict__ W_in_s,
    const float* __restrict__ W_in_v, float* __restrict__ h)
{
  __shared__ float sh[16][4][64];
  int wave = threadIdx.x >> 6, lane = threadIdx.x & 63;
  int nb = blockIdx.x*16 + wave*4;
  #pragma unroll
  for(int k=0;k<4;++k){
    int nd = wave*4 + k;
    float4 nf = *(const float4*)(node_feats + (size_t)((nb+k)*64 + lane)*4);
    sh[nd][0][lane]=nf.x; sh[nd][1][lane]=nf.y; sh[nd][2][lane]=nf.z; sh[nd][3][lane]=nf.w;
  }
  __syncthreads();
  float as[4]={0,0,0,0}, a0[4]={0,0,0,0}, a1[4]={0,0,0,0}, a2[4]={0,0,0,0};
  for(int f=0; f<64; ++f){
    float ws = W_in_s[f*64+lane], wv = W_in_v[f*64+lane];
    #pragma unroll
    for(int k=0;k<4;++k){
      int nd = wave*4 + k;
      as[k] = fmaf(sh[nd][0][f], ws, as[k]);
      a0[k] = fmaf(sh[nd][1][f], wv, a0[k]);
      a1[k] = fmaf(sh[nd][2][f], wv, a1[k]);
      a2[k] = fmaf(sh[nd][3][f], wv, a2[k]);
    }
  }
  #pragma unroll
  for(int k=0;k<4;++k){
    float4 o4; o4.x = as[k]*0.125f; o4.y = a0[k]*0.125f;
    o4.z = a1[k]*0.125f; o4.w = a2[k]*0.125f;
    *(float4*)(h + (size_t)((nb+k)*64 + lane)*4) = o4;
  }
}

// ---------------- edge kernel over receiver-sorted data ----------------
__global__ __launch_bounds__(256) void k_edge(
    const float* __restrict__ srt_y, const float* __restrict__ srt_rad,
    const int* __restrict__ srt_snd, const int* __restrict__ srt_rcv,
    const float* __restrict__ mlp_w1, const float* __restrict__ mlp_w2,
    const float* __restrict__ h, float* __restrict__ agg)
{
  __shared__ int   sndS[4][TB];
  __shared__ int   rcvS[4][TB];
  __shared__ float yS[4][4*TB];
  __shared__ float rad[4][8*TB];
  __shared__ float hid[4][TB][64];
  int wave = threadIdx.x >> 6, lane = threadIdx.x & 63;
  int e0 = (blockIdx.x*4 + wave)*TB;

  // All LDS below is wave-local: no block barriers needed (wave64 lockstep).
  if(lane < TB){
    sndS[wave][lane] = srt_snd[e0 + lane];
    rcvS[wave][lane] = srt_rcv[e0 + lane];
  }
  yS[wave][lane]     = srt_y[(size_t)e0*4 + lane];
  rad[wave][lane]    = srt_rad[(size_t)e0*8 + lane];
  rad[wave][64+lane] = srt_rad[(size_t)e0*8 + 64 + lane];
  float wl[8];
  #pragma unroll
  for(int r=0;r<8;++r) wl[r] = mlp_w1[r*64+lane];

  // hidden = silu(rad @ w1), lane = hidden unit
  #pragma unroll
  for(int t=0;t<TB;++t){
    float acc = 0.f;
    #pragma unroll
    for(int r=0;r<8;++r) acc = fmaf(rad[wave][t*8+r], wl[r], acc);
    hid[wave][t][lane] = acc / (1.f + __expf(-acc));
  }

  // w[j][t] = hidden[t] @ w2[:, j*64+lane]
  float w[5][TB];
  #pragma unroll
  for(int j=0;j<5;++j)
    #pragma unroll
    for(int t=0;t<TB;++t) w[j][t] = 0.f;
  for(int hh=0; hh<64; hh+=2){
    float b0[5], b1[5];
    #pragma unroll
    for(int j=0;j<5;++j){
      b0[j] = mlp_w2[hh*320     + j*64 + lane];
      b1[j] = mlp_w2[(hh+1)*320 + j*64 + lane];
    }
    #pragma unroll
    for(int t=0;t<TB;++t){
      float2 hb = *(const float2*)&hid[wave][t][hh];
      #pragma unroll
      for(int j=0;j<5;++j) w[j][t] = fmaf(hb.x, b0[j], fmaf(hb.y, b1[j], w[j][t]));
    }
  }

  // message build + register-run accumulation; h gathered as one float4, 4-deep pipeline
  float4 hv[4];
  #pragma unroll
  for(int p=0;p<4;++p)
    hv[p] = *(const float4*)(h + (size_t)(sndS[wave][p]*64 + lane)*4);

  float as_=0.f, av0=0.f, av1=0.f, av2=0.f;
  int cur = rcvS[wave][0];
  #pragma unroll
  for(int t=0;t<TB;++t){
    float4 hc = hv[t&3];
    if(t+4 < TB)
      hv[t&3] = *(const float4*)(h + (size_t)(sndS[wave][t+4]*64 + lane)*4);
    int rcv = rcvS[wave][t];
    if(rcv != cur){
      size_t ro = (size_t)(cur*64 + lane)*4;
      atomicAdd(&agg[ro],   as_);
      atomicAdd(&agg[ro+1], av0);
      atomicAdd(&agg[ro+2], av1);
      atomicAdd(&agg[ro+3], av2);
      as_=0.f; av0=0.f; av1=0.f; av2=0.f;
      cur = rcv;
    }
    float y0=yS[wave][t*4], y1=yS[wave][t*4+1], y2=yS[wave][t*4+2];
    float ss=hc.x, sv0=hc.y, sv1=hc.z, sv2=hc.w;
    float dot = sv0*y0 + sv1*y1 + sv2*y2;
    as_ += w[0][t]*ss + w[1][t]*dot;
    float w2s = w[2][t]*ss, w3t = w[3][t], w4t = w[4][t];
    av0 += w2s*y0 + w3t*sv0 + w4t*(sv1*y2 - sv2*y1);
    av1 += w2s*y1 + w3t*sv1 + w4t*(sv2*y0 - sv0*y2);
    av2 += w2s*y2 + w3t*sv2 + w4t*(sv0*y1 - sv1*y0);
  }
  size_t ro = (size_t)(cur*64 + lane)*4;
  atomicAdd(&agg[ro],   as_);
  atomicAdd(&agg[ro+1], av0);
  atomicAdd(&agg[ro+2], av1);
  atomicAdd(&agg[ro+3], av2);
}

// ---------------- node post-pass: 4 nodes per wave ----------------
__global__ __launch_bounds__(256) void k_node_post(
  const float* __restrict__ node_feats, const int* __restrict__ specie,
  const float* __restrict__ agg,
  const float* __restrict__ Wrst, const float* __restrict__ Wrvt,
  const float* __restrict__ W_out_s, const float* __restrict__ W_out_v,
  const float* __restrict__ W_prod_s, const float* __restrict__ W_prod_v,
  const float* __restrict__ W_lin_s, const float* __restrict__ W_lin_v,
  const float* __restrict__ W_read, float* __restrict__ out_node,
  float* __restrict__ out_feats)
{
  __shared__ float shA[16][4][64];
  __shared__ float shS[16][4][64];   // node_feats first, reused for p_s/p_v
  int wave = threadIdx.x >> 6, lane = threadIdx.x & 63;
  int nb = blockIdx.x*16 + wave*4;
  #pragma unroll
  for(int k=0;k<4;++k){
    int nd = wave*4 + k;
    float4 ag = *(const float4*)(agg + (size_t)((nb+k)*64 + lane)*4);
    shA[nd][0][lane] = ag.x * (1.f/16.f);
    shA[nd][1][lane] = ag.y * (1.f/16.f);
    shA[nd][2][lane] = ag.z * (1.f/16.f);
    shA[nd][3][lane] = ag.w * (1.f/16.f);
    float4 nf = *(const float4*)(node_feats + (size_t)((nb+k)*64 + lane)*4);
    shS[nd][0][lane]=nf.x; shS[nd][1][lane]=nf.y; shS[nd][2][lane]=nf.z; shS[nd][3][lane]=nf.w;
  }
  int spec[4];
  #pragma unroll
  for(int k=0;k<4;++k) spec[k] = specie[nb+k];
  __syncthreads();
  float a_s[4]={0,0,0,0}, a0[4]={0,0,0,0}, a1[4]={0,0,0,0}, a2[4]={0,0,0,0};
  float r_s[4]={0,0,0,0}, r0[4]={0,0,0,0}, r1[4]={0,0,0,0}, r2[4]={0,0,0,0};
  for(int f=0; f<64; ++f){
    float wos = W_out_s[f*64+lane], wov = W_out_v[f*64+lane];
    #pragma unroll
    for(int k=0;k<4;++k){
      int nd = wave*4 + k;
      a_s[k] = fmaf(shA[nd][0][f], wos, a_s[k]);
      a0[k]  = fmaf(shA[nd][1][f], wov, a0[k]);
      a1[k]  = fmaf(shA[nd][2][f], wov, a1[k]);
      a2[k]  = fmaf(shA[nd][3][f], wov, a2[k]);
    }
    #pragma unroll
    for(int k=0;k<4;++k){
      int nd = wave*4 + k;
      float wrs = Wrst[spec[k]*4096 + f*64 + lane];
      float wrv = Wrvt[spec[k]*4096 + f*64 + lane];
      r_s[k] = fmaf(shS[nd][0][f], wrs, r_s[k]);
      r0[k]  = fmaf(shS[nd][1][f], wrv, r0[k]);
      r1[k]  = fmaf(shS[nd][2][f], wrv, r1[k]);
      r2[k]  = fmaf(shS[nd][3][f], wrv, r2[k]);
    }
  }
  __syncthreads();
  #pragma unroll
  for(int k=0;k<4;++k){
    int nd = wave*4 + k;
    float A_s = a_s[k]*0.125f, A0 = a0[k]*0.125f, A1 = a1[k]*0.125f, A2 = a2[k]*0.125f;
    float vv = A0*A0 + A1*A1 + A2*A2;
    float as2 = A_s*A_s;
    const float* Wp = W_prod_s + spec[k]*320;
    float p_s = Wp[lane]*A_s + Wp[64+lane]*as2 + Wp[128+lane]*as2*A_s
              + Wp[192+lane]*vv + Wp[256+lane]*A_s*vv;
    const float* Wq = W_prod_v + spec[k]*256;
    float coef = Wq[lane] + Wq[64+lane]*A_s + Wq[128+lane]*as2 + Wq[192+lane]*vv;
    shS[nd][0][lane] = p_s;
    shS[nd][1][lane] = coef*A0;
    shS[nd][2][lane] = coef*A1;
    shS[nd][3][lane] = coef*A2;
  }
  __syncthreads();
  float lfs[4]={0,0,0,0}, lf0[4]={0,0,0,0}, lf1[4]={0,0,0,0}, lf2[4]={0,0,0,0};
  for(int f=0; f<64; ++f){
    float wls = W_lin_s[f*64+lane], wlv = W_lin_v[f*64+lane];
    #pragma unroll
    for(int k=0;k<4;++k){
      int nd = wave*4 + k;
      lfs[k] = fmaf(shS[nd][0][f], wls, lfs[k]);
      lf0[k] = fmaf(shS[nd][1][f], wlv, lf0[k]);
      lf1[k] = fmaf(shS[nd][2][f], wlv, lf1[k]);
      lf2[k] = fmaf(shS[nd][3][f], wlv, lf2[k]);
    }
  }
  float wr = W_read[lane];
  #pragma unroll
  for(int k=0;k<4;++k){
    int n = nb + k;
    float FS = lfs[k]*0.125f + r_s[k]*0.125f;
    float F0 = lf0[k]*0.125f + r0[k]*0.125f;
    float F1 = lf1[k]*0.125f + r1[k]*0.125f;
    float F2 = lf2[k]*0.125f + r2[k]*0.125f;
    float x = FS * wr;
    #pragma unroll
    for(int off=32; off; off>>=1) x += __shfl_down(x, off);
    if(lane==0) out_node[n] = x*0.125f;
    float4 o4; o4.x=FS; o4.y=F0; o4.z=F1; o4.w=F2;
    *(float4*)(out_feats + (size_t)(n*64+lane)*4) = o4;
  }
}

extern "C" void kernel_launch(void* const* d_in, const int* in_sizes, int n_in,
                              void* d_out, int out_size, void* d_ws, size_t ws_size,
                              hipStream_t stream) {
  const float* vectors    = (const float*)d_in[0];
  const float* node_feats = (const float*)d_in[1];
  const int*   node_specie= (const int*)  d_in[2];
  const float* radial     = (const float*)d_in[3];
  const int*   senders    = (const int*)  d_in[4];
  const int*   receivers  = (const int*)  d_in[5];
  const float* W_res_s    = (const float*)d_in[6];
  const float* W_res_v    = (const float*)d_in[7];
  const float* W_in_s     = (const float*)d_in[8];
  const float* W_in_v     = (const float*)d_in[9];
  const float* mlp_w1     = (const float*)d_in[10];
  const float* mlp_w2     = (const float*)d_in[11];
  const float* W_out_s    = (const float*)d_in[12];
  const float* W_out_v    = (const float*)d_in[13];
  const float* W_prod_s   = (const float*)d_in[14];
  const float* W_prod_v   = (const float*)d_in[15];
  const float* W_lin_s    = (const float*)d_in[16];
  const float* W_lin_v    = (const float*)d_in[17];
  const float* W_read     = (const float*)d_in[18];

  float* ws   = (float*)d_ws;
  float* h    = ws;                          // 4*NF floats, [(n*64+lane)*4+c]
  float* agg  = ws + 4*(size_t)NF;           // 4*NF floats, same layout
  float* Wrst = ws + 8*(size_t)NF;           // 40960
  float* Wrvt = Wrst + 40960;                // 40960
  float* srt_rad = Wrvt + 40960;             // 8*NE
  float* srt_y   = srt_rad + 8*(size_t)NE;   // 4*NE
  int*   srt_snd = (int*)(srt_y + 4*(size_t)NE); // NE
  int*   srt_rcv = srt_snd + NE;             // NE
  int*   rank    = srt_rcv + NE;             // NE
  int*   offset  = rank + NE;                // NN+1
  int*   count   = offset + NN + 1;          // NN

  hipMemsetAsync(agg,   0, (size_t)4*NF*sizeof(float), stream);
  hipMemsetAsync(count, 0, (size_t)NN*sizeof(int), stream);
  k_transpose_res<<<160, 256, 0, stream>>>(W_res_s, W_res_v, Wrst, Wrvt);
  k_hist_rank<<<NE/256, 256, 0, stream>>>(receivers, count, rank);
  k_scan     <<<1,      256, 0, stream>>>(count, offset);
  k_scatter  <<<NE/256, 256, 0, stream>>>(senders, receivers, vectors, radial,
                                          offset, rank, srt_snd, srt_rcv, srt_y, srt_rad);
  k_node_pre<<<NN/16, 256, 0, stream>>>(node_feats, W_in_s, W_in_v, h);
  k_edge<<<NE/(4*TB), 256, 0, stream>>>(srt_y, srt_rad, srt_snd, srt_rcv,
                                        mlp_w1, mlp_w2, h, agg);
  k_node_post<<<NN/16, 256, 0, stream>>>(node_feats, node_specie, agg,
                                         Wrst, Wrvt, W_out_s, W_out_v,
                                         W_prod_s, W_prod_v, W_lin_s, W_lin_v,
                                         W_read, (float*)d_out, (float*)d_out + NN);
}

// Round 3
// 483.764 us; speedup vs baseline: 1.1095x; 1.1095x over previous
//
#include <hip/hip_runtime.h>
#include <math.h>

#define NN 20000
#define NE 320000
#define NF (NN*64)
#define TB 16

typedef float v2f __attribute__((ext_vector_type(2)));

#if __has_builtin(__builtin_elementwise_fma)
#define PKFMA(a,b,c) __builtin_elementwise_fma(a,b,c)
#else
static __device__ __forceinline__ v2f PKFMA(v2f a, v2f b, v2f c){
  v2f r; r.x = fmaf(a.x,b.x,c.x); r.y = fmaf(a.y,b.y,c.y); return r;
}
#endif

// ---------------- weight transpose ----------------
__global__ __launch_bounds__(256) void k_transpose_res(
    const float* __restrict__ Ws, const float* __restrict__ Wv,
    float* __restrict__ Wst, float* __restrict__ Wvt)
{
  int i = blockIdx.x*256 + threadIdx.x;   // 0..40959
  int spec = i >> 12;
  int g = (i >> 6) & 63;
  int f = i & 63;
  Wst[spec*4096 + f*64 + g] = Ws[i];
  Wvt[spec*4096 + f*64 + g] = Wv[i];
}

// ---------------- counting sort of edges by receiver ----------------
__global__ __launch_bounds__(256) void k_hist_rank(const int* __restrict__ receivers,
                                                   int* __restrict__ count,
                                                   int* __restrict__ rank)
{
  int e = blockIdx.x*256 + threadIdx.x;
  rank[e] = atomicAdd(&count[receivers[e]], 1);
}

__global__ __launch_bounds__(256) void k_scan(const int* __restrict__ count,
                                              int* __restrict__ offset)
{
  __shared__ int part[256];
  int t = threadIdx.x;
  const int PER = 79;                     // 256*79 = 20224 >= NN
  int s = 0;
  for(int i=0;i<PER;++i){ int idx = t*PER+i; if(idx < NN) s += count[idx]; }
  part[t] = s;
  __syncthreads();
  for(int off=1; off<256; off<<=1){
    int v = (t>=off) ? part[t-off] : 0;
    __syncthreads();
    part[t] += v;
    __syncthreads();
  }
  int run = t ? part[t-1] : 0;
  for(int i=0;i<PER;++i){
    int idx = t*PER+i;
    if(idx < NN){ offset[idx] = run; run += count[idx]; }
  }
  if(t==255) offset[NN] = run;
}

// Scatter edge data into one 64-B record per edge (receiver-sorted).
// rec layout (16 floats): [0..2]=yhat, [3]=snd(bits), [4..11]=rad, [12]=rcv(bits), [13..15]=pad
__global__ __launch_bounds__(256) void k_scatter(
    const int* __restrict__ senders, const int* __restrict__ receivers,
    const float* __restrict__ vectors, const float* __restrict__ radial,
    const int* __restrict__ offset, const int* __restrict__ rank,
    float* __restrict__ rec)
{
  int e = blockIdx.x*256 + threadIdx.x;
  int r = receivers[e];
  int slot = offset[r] + rank[e];
  float vx = vectors[e*3], vy = vectors[e*3+1], vz = vectors[e*3+2];
  float rinv = rsqrtf(vx*vx + vy*vy + vz*vz + 1e-12f);
  float4 ra = *(const float4*)(radial + (size_t)e*8);
  float4 rb = *(const float4*)(radial + (size_t)e*8 + 4);
  float* rp = rec + (size_t)slot*16;
  float4 w0; w0.x = vx*rinv; w0.y = vy*rinv; w0.z = vz*rinv; w0.w = __int_as_float(senders[e]);
  float4 w3; w3.x = __int_as_float(r); w3.y = 0.f; w3.z = 0.f; w3.w = 0.f;
  *(float4*)(rp)      = w0;
  *(float4*)(rp + 4)  = ra;
  *(float4*)(rp + 8)  = rb;
  *(float4*)(rp + 12) = w3;
}

// ---------------- node pre-pass: 4 nodes per wave ----------------
// h layout: h[(n*64+lane)*4 + c]  (float4 per lane, gather-friendly)
__global__ __launch_bounds__(256) void k_node_pre(
    const float* __restrict__ node_feats, const float* __restrict__ W_in_s,
    const float* __restrict__ W_in_v, float* __restrict__ h)
{
  __shared__ float sh[16][4][64];
  int wave = threadIdx.x >> 6, lane = threadIdx.x & 63;
  int nb = blockIdx.x*16 + wave*4;
  #pragma unroll
  for(int k=0;k<4;++k){
    int nd = wave*4 + k;
    float4 nf = *(const float4*)(node_feats + (size_t)((nb+k)*64 + lane)*4);
    sh[nd][0][lane]=nf.x; sh[nd][1][lane]=nf.y; sh[nd][2][lane]=nf.z; sh[nd][3][lane]=nf.w;
  }
  __syncthreads();
  float as[4]={0,0,0,0}, a0[4]={0,0,0,0}, a1[4]={0,0,0,0}, a2[4]={0,0,0,0};
  for(int f=0; f<64; ++f){
    float ws = W_in_s[f*64+lane], wv = W_in_v[f*64+lane];
    #pragma unroll
    for(int k=0;k<4;++k){
      int nd = wave*4 + k;
      as[k] = fmaf(sh[nd][0][f], ws, as[k]);
      a0[k] = fmaf(sh[nd][1][f], wv, a0[k]);
      a1[k] = fmaf(sh[nd][2][f], wv, a1[k]);
      a2[k] = fmaf(sh[nd][3][f], wv, a2[k]);
    }
  }
  #pragma unroll
  for(int k=0;k<4;++k){
    float4 o4; o4.x = as[k]*0.125f; o4.y = a0[k]*0.125f;
    o4.z = a1[k]*0.125f; o4.w = a2[k]*0.125f;
    *(float4*)(h + (size_t)((nb+k)*64 + lane)*4) = o4;
  }
}

// ---------------- edge kernel over packed receiver-sorted records ----------------
// agg layout: agg[node*256 + c*64 + lane]  (channel-planar: contiguous atomics)
__global__ __launch_bounds__(256) void k_edge(
    const float* __restrict__ rec,
    const float* __restrict__ mlp_w1, const float* __restrict__ mlp_w2,
    const float* __restrict__ h, float* __restrict__ agg)
{
  __shared__ float recS[4][256];        // 16 edges x 16 floats, wave-local
  __shared__ float hid[4][64][20];      // [h][t], stride 20 keeps 16B align; reads broadcast
  int wave = threadIdx.x >> 6, lane = threadIdx.x & 63;
  int e0 = (blockIdx.x*4 + wave)*TB;

  // stage records: 1 KB per wave in one dwordx4
  *(float4*)&recS[wave][lane*4] = *(const float4*)(rec + (size_t)e0*16 + lane*4);

  float wl[8];
  #pragma unroll
  for(int r=0;r<8;++r) wl[r] = mlp_w1[r*64+lane];

  // hidden = silu(rad @ w1), lane = hidden unit; store transposed [h][t]
  #pragma unroll
  for(int t=0;t<TB;++t){
    float acc = 0.f;
    #pragma unroll
    for(int r=0;r<8;++r) acc = fmaf(recS[wave][t*16+4+r], wl[r], acc);
    hid[wave][lane][t] = acc / (1.f + __expf(-acc));
  }

  // w[j][t-pair] = sum_h hid[h][t-pair] * w2[h][j*64+lane]  -- packed fp32
  v2f wv[5][8];
  #pragma unroll
  for(int j=0;j<5;++j)
    #pragma unroll
    for(int tp=0;tp<8;++tp) wv[j][tp] = (v2f){0.f, 0.f};
  const float* w2p = mlp_w2 + lane;
  for(int hh=0; hh<64; ++hh){
    float b[5];
    #pragma unroll
    for(int j=0;j<5;++j) b[j] = w2p[hh*320 + j*64];
    v2f hv[8];
    #pragma unroll
    for(int tp=0;tp<8;++tp) hv[tp] = *(const v2f*)&hid[wave][hh][2*tp];
    #pragma unroll
    for(int j=0;j<5;++j){
      v2f bb = {b[j], b[j]};
      #pragma unroll
      for(int tp=0;tp<8;++tp) wv[j][tp] = PKFMA(bb, hv[tp], wv[j][tp]);
    }
  }

  // message build + register-run accumulation; h gathered as one float4, 4-deep pipeline
  float4 hv4[4];
  #pragma unroll
  for(int p=0;p<4;++p){
    int snd = __float_as_int(recS[wave][p*16+3]);
    hv4[p] = *(const float4*)(h + (size_t)(snd*64 + lane)*4);
  }

  float as_=0.f, av0=0.f, av1=0.f, av2=0.f;
  int cur = __float_as_int(recS[wave][12]);
  #pragma unroll
  for(int t=0;t<TB;++t){
    float4 hc = hv4[t&3];
    if(t+4 < TB){
      int snd = __float_as_int(recS[wave][(t+4)*16+3]);
      hv4[t&3] = *(const float4*)(h + (size_t)(snd*64 + lane)*4);
    }
    int rcv = __float_as_int(recS[wave][t*16+12]);
    if(rcv != cur){
      size_t ro = (size_t)cur*256 + lane;
      atomicAdd(&agg[ro],     as_);
      atomicAdd(&agg[ro+64],  av0);
      atomicAdd(&agg[ro+128], av1);
      atomicAdd(&agg[ro+192], av2);
      as_=0.f; av0=0.f; av1=0.f; av2=0.f;
      cur = rcv;
    }
    float y0=recS[wave][t*16], y1=recS[wave][t*16+1], y2=recS[wave][t*16+2];
    float ss=hc.x, sv0=hc.y, sv1=hc.z, sv2=hc.w;
    float dot = sv0*y0 + sv1*y1 + sv2*y2;
    float wt0 = wv[0][t>>1][t&1], wt1 = wv[1][t>>1][t&1];
    float wt2 = wv[2][t>>1][t&1], wt3 = wv[3][t>>1][t&1], wt4 = wv[4][t>>1][t&1];
    as_ += wt0*ss + wt1*dot;
    float w2s = wt2*ss;
    av0 += w2s*y0 + wt3*sv0 + wt4*(sv1*y2 - sv2*y1);
    av1 += w2s*y1 + wt3*sv1 + wt4*(sv2*y0 - sv0*y2);
    av2 += w2s*y2 + wt3*sv2 + wt4*(sv0*y1 - sv1*y0);
  }
  size_t ro = (size_t)cur*256 + lane;
  atomicAdd(&agg[ro],     as_);
  atomicAdd(&agg[ro+64],  av0);
  atomicAdd(&agg[ro+128], av1);
  atomicAdd(&agg[ro+192], av2);
}

// ---------------- node post-pass: 4 nodes per wave ----------------
__global__ __launch_bounds__(256) void k_node_post(
  const float* __restrict__ node_feats, const int* __restrict__ specie,
  const float* __restrict__ agg,
  const float* __restrict__ Wrst, const float* __restrict__ Wrvt,
  const float* __restrict__ W_out_s, const float* __restrict__ W_out_v,
  const float* __restrict__ W_prod_s, const float* __restrict__ W_prod_v,
  const float* __restrict__ W_lin_s, const float* __restrict__ W_lin_v,
  const float* __restrict__ W_read, float* __restrict__ out_node,
  float* __restrict__ out_feats)
{
  __shared__ float shA[16][4][64];
  __shared__ float shS[16][4][64];   // node_feats first, reused for p_s/p_v
  int wave = threadIdx.x >> 6, lane = threadIdx.x & 63;
  int nb = blockIdx.x*16 + wave*4;
  #pragma unroll
  for(int k=0;k<4;++k){
    int nd = wave*4 + k;
    size_t o = (size_t)(nb+k)*256 + lane;
    shA[nd][0][lane] = agg[o]      * (1.f/16.f);
    shA[nd][1][lane] = agg[o+64]   * (1.f/16.f);
    shA[nd][2][lane] = agg[o+128]  * (1.f/16.f);
    shA[nd][3][lane] = agg[o+192]  * (1.f/16.f);
    float4 nf = *(const float4*)(node_feats + (size_t)((nb+k)*64 + lane)*4);
    shS[nd][0][lane]=nf.x; shS[nd][1][lane]=nf.y; shS[nd][2][lane]=nf.z; shS[nd][3][lane]=nf.w;
  }
  int spec[4];
  #pragma unroll
  for(int k=0;k<4;++k) spec[k] = specie[nb+k];
  __syncthreads();
  float a_s[4]={0,0,0,0}, a0[4]={0,0,0,0}, a1[4]={0,0,0,0}, a2[4]={0,0,0,0};
  float r_s[4]={0,0,0,0}, r0[4]={0,0,0,0}, r1[4]={0,0,0,0}, r2[4]={0,0,0,0};
  for(int f=0; f<64; ++f){
    float wos = W_out_s[f*64+lane], wov = W_out_v[f*64+lane];
    #pragma unroll
    for(int k=0;k<4;++k){
      int nd = wave*4 + k;
      a_s[k] = fmaf(shA[nd][0][f], wos, a_s[k]);
      a0[k]  = fmaf(shA[nd][1][f], wov, a0[k]);
      a1[k]  = fmaf(shA[nd][2][f], wov, a1[k]);
      a2[k]  = fmaf(shA[nd][3][f], wov, a2[k]);
    }
    #pragma unroll
    for(int k=0;k<4;++k){
      int nd = wave*4 + k;
      float wrs = Wrst[spec[k]*4096 + f*64 + lane];
      float wrv = Wrvt[spec[k]*4096 + f*64 + lane];
      r_s[k] = fmaf(shS[nd][0][f], wrs, r_s[k]);
      r0[k]  = fmaf(shS[nd][1][f], wrv, r0[k]);
      r1[k]  = fmaf(shS[nd][2][f], wrv, r1[k]);
      r2[k]  = fmaf(shS[nd][3][f], wrv, r2[k]);
    }
  }
  __syncthreads();
  #pragma unroll
  for(int k=0;k<4;++k){
    int nd = wave*4 + k;
    float A_s = a_s[k]*0.125f, A0 = a0[k]*0.125f, A1 = a1[k]*0.125f, A2 = a2[k]*0.125f;
    float vv = A0*A0 + A1*A1 + A2*A2;
    float as2 = A_s*A_s;
    const float* Wp = W_prod_s + spec[k]*320;
    float p_s = Wp[lane]*A_s + Wp[64+lane]*as2 + Wp[128+lane]*as2*A_s
              + Wp[192+lane]*vv + Wp[256+lane]*A_s*vv;
    const float* Wq = W_prod_v + spec[k]*256;
    float coef = Wq[lane] + Wq[64+lane]*A_s + Wq[128+lane]*as2 + Wq[192+lane]*vv;
    shS[nd][0][lane] = p_s;
    shS[nd][1][lane] = coef*A0;
    shS[nd][2][lane] = coef*A1;
    shS[nd][3][lane] = coef*A2;
  }
  __syncthreads();
  float lfs[4]={0,0,0,0}, lf0[4]={0,0,0,0}, lf1[4]={0,0,0,0}, lf2[4]={0,0,0,0};
  for(int f=0; f<64; ++f){
    float wls = W_lin_s[f*64+lane], wlv = W_lin_v[f*64+lane];
    #pragma unroll
    for(int k=0;k<4;++k){
      int nd = wave*4 + k;
      lfs[k] = fmaf(shS[nd][0][f], wls, lfs[k]);
      lf0[k] = fmaf(shS[nd][1][f], wlv, lf0[k]);
      lf1[k] = fmaf(shS[nd][2][f], wlv, lf1[k]);
      lf2[k] = fmaf(shS[nd][3][f], wlv, lf2[k]);
    }
  }
  float wr = W_read[lane];
  #pragma unroll
  for(int k=0;k<4;++k){
    int n = nb + k;
    float FS = lfs[k]*0.125f + r_s[k]*0.125f;
    float F0 = lf0[k]*0.125f + r0[k]*0.125f;
    float F1 = lf1[k]*0.125f + r1[k]*0.125f;
    float F2 = lf2[k]*0.125f + r2[k]*0.125f;
    float x = FS * wr;
    #pragma unroll
    for(int off=32; off; off>>=1) x += __shfl_down(x, off);
    if(lane==0) out_node[n] = x*0.125f;
    float4 o4; o4.x=FS; o4.y=F0; o4.z=F1; o4.w=F2;
    *(float4*)(out_feats + (size_t)(n*64+lane)*4) = o4;
  }
}

extern "C" void kernel_launch(void* const* d_in, const int* in_sizes, int n_in,
                              void* d_out, int out_size, void* d_ws, size_t ws_size,
                              hipStream_t stream) {
  const float* vectors    = (const float*)d_in[0];
  const float* node_feats = (const float*)d_in[1];
  const int*   node_specie= (const int*)  d_in[2];
  const float* radial     = (const float*)d_in[3];
  const int*   senders    = (const int*)  d_in[4];
  const int*   receivers  = (const int*)  d_in[5];
  const float* W_res_s    = (const float*)d_in[6];
  const float* W_res_v    = (const float*)d_in[7];
  const float* W_in_s     = (const float*)d_in[8];
  const float* W_in_v     = (const float*)d_in[9];
  const float* mlp_w1     = (const float*)d_in[10];
  const float* mlp_w2     = (const float*)d_in[11];
  const float* W_out_s    = (const float*)d_in[12];
  const float* W_out_v    = (const float*)d_in[13];
  const float* W_prod_s   = (const float*)d_in[14];
  const float* W_prod_v   = (const float*)d_in[15];
  const float* W_lin_s    = (const float*)d_in[16];
  const float* W_lin_v    = (const float*)d_in[17];
  const float* W_read     = (const float*)d_in[18];

  float* ws   = (float*)d_ws;
  float* h    = ws;                          // 4*NF floats, [(n*64+lane)*4+c]
  float* agg  = ws + 4*(size_t)NF;           // 4*NF floats, [n*256 + c*64 + lane]
  float* Wrst = ws + 8*(size_t)NF;           // 40960
  float* Wrvt = Wrst + 40960;                // 40960
  float* rec  = Wrvt + 40960;                // 16*NE floats (64 B per edge)
  int*   rank   = (int*)(rec + 16*(size_t)NE); // NE
  int*   offset = rank + NE;                 // NN+1
  int*   count  = offset + NN + 1;           // NN

  hipMemsetAsync(agg,   0, (size_t)4*NF*sizeof(float), stream);
  hipMemsetAsync(count, 0, (size_t)NN*sizeof(int), stream);
  k_transpose_res<<<160, 256, 0, stream>>>(W_res_s, W_res_v, Wrst, Wrvt);
  k_hist_rank<<<NE/256, 256, 0, stream>>>(receivers, count, rank);
  k_scan     <<<1,      256, 0, stream>>>(count, offset);
  k_scatter  <<<NE/256, 256, 0, stream>>>(senders, receivers, vectors, radial,
                                          offset, rank, rec);
  k_node_pre<<<NN/16, 256, 0, stream>>>(node_feats, W_in_s, W_in_v, h);
  k_edge<<<NE/(4*TB), 256, 0, stream>>>(rec, mlp_w1, mlp_w2, h, agg);
  k_node_post<<<NN/16, 256, 0, stream>>>(node_feats, node_specie, agg,
                                         Wrst, Wrvt, W_out_s, W_out_v,
                                         W_prod_s, W_prod_v, W_lin_s, W_lin_v,
                                         W_read, (float*)d_out, (float*)d_out + NN);
}

// Round 5
// 458.784 us; speedup vs baseline: 1.1699x; 1.0544x over previous
//
#include <hip/hip_runtime.h>
#include <math.h>

#define NN 20000
#define NE 320000
#define NF (NN*64)
#define TB 16

typedef float v2f __attribute__((ext_vector_type(2)));

#if __has_builtin(__builtin_elementwise_fma)
#define PKFMA(a,b,c) __builtin_elementwise_fma(a,b,c)
#else
static __device__ __forceinline__ v2f PKFMA(v2f a, v2f b, v2f c){
  v2f r; r.x = fmaf(a.x,b.x,c.x); r.y = fmaf(a.y,b.y,c.y); return r;
}
#endif

// ---------------- fused: receiver histogram+rank AND residual-weight transpose ----------------
__global__ __launch_bounds__(256) void k_hist_prep(
    const int* __restrict__ receivers, int* __restrict__ count, int* __restrict__ rank,
    const float* __restrict__ Ws, const float* __restrict__ Wv,
    float* __restrict__ Wst, float* __restrict__ Wvt)
{
  int e = blockIdx.x*256 + threadIdx.x;
  rank[e] = atomicAdd(&count[receivers[e]], 1);
  if(blockIdx.x < 160){
    int i = blockIdx.x*256 + threadIdx.x;   // 0..40959
    int spec = i >> 12;
    int g = (i >> 6) & 63;
    int f = i & 63;
    Wst[spec*4096 + f*64 + g] = Ws[i];
    Wvt[spec*4096 + f*64 + g] = Wv[i];
  }
}

// ---------------- exclusive scan over 20000 counts: 1024 threads, reg-cached ----------------
__global__ __launch_bounds__(1024) void k_scan(const int* __restrict__ count,
                                               int* __restrict__ offset)
{
  __shared__ int part[1024];
  int t = threadIdx.x;
  const int PER = 20;                      // 1024*20 = 20480 >= NN
  int base = t*PER;
  int loc[PER];
  int s = 0;
  #pragma unroll
  for(int i=0;i<PER;++i){
    int idx = base+i;
    int v = (idx < NN) ? count[idx] : 0;
    loc[i] = v; s += v;
  }
  part[t] = s;
  __syncthreads();
  for(int off=1; off<1024; off<<=1){
    int v = (t>=off) ? part[t-off] : 0;
    __syncthreads();
    part[t] += v;
    __syncthreads();
  }
  int run = t ? part[t-1] : 0;
  #pragma unroll
  for(int i=0;i<PER;++i){
    int idx = base+i;
    if(idx < NN) offset[idx] = run;
    run += loc[i];
  }
  if(t==1023) offset[NN] = part[1023];
}

// Scatter edge data into one 64-B record per edge (receiver-sorted).
// rec layout (16 floats): [0..2]=yhat, [3]=snd(bits), [4..11]=rad, [12]=rcv(bits), [13..15]=pad
__global__ __launch_bounds__(256) void k_scatter(
    const int* __restrict__ senders, const int* __restrict__ receivers,
    const float* __restrict__ vectors, const float* __restrict__ radial,
    const int* __restrict__ offset, const int* __restrict__ rank,
    float* __restrict__ rec)
{
  int e = blockIdx.x*256 + threadIdx.x;
  int r = receivers[e];
  int slot = offset[r] + rank[e];
  float vx = vectors[e*3], vy = vectors[e*3+1], vz = vectors[e*3+2];
  float rinv = rsqrtf(vx*vx + vy*vy + vz*vz + 1e-12f);
  float4 ra = *(const float4*)(radial + (size_t)e*8);
  float4 rb = *(const float4*)(radial + (size_t)e*8 + 4);
  float* rp = rec + (size_t)slot*16;
  float4 w0; w0.x = vx*rinv; w0.y = vy*rinv; w0.z = vz*rinv; w0.w = __int_as_float(senders[e]);
  float4 w3; w3.x = __int_as_float(r); w3.y = 0.f; w3.z = 0.f; w3.w = 0.f;
  *(float4*)(rp)      = w0;
  *(float4*)(rp + 4)  = ra;
  *(float4*)(rp + 8)  = rb;
  *(float4*)(rp + 12) = w3;
}

// ---------------- node pre-pass: 4 nodes per wave ----------------
// h layout: h[(n*64+lane)*4 + c]  (float4 per lane, gather-friendly)
__global__ __launch_bounds__(256) void k_node_pre(
    const float* __restrict__ node_feats, const float* __restrict__ W_in_s,
    const float* __restrict__ W_in_v, float* __restrict__ h)
{
  __shared__ float sh[16][4][64];
  int wave = threadIdx.x >> 6, lane = threadIdx.x & 63;
  int nb = blockIdx.x*16 + wave*4;
  #pragma unroll
  for(int k=0;k<4;++k){
    int nd = wave*4 + k;
    float4 nf = *(const float4*)(node_feats + (size_t)((nb+k)*64 + lane)*4);
    sh[nd][0][lane]=nf.x; sh[nd][1][lane]=nf.y; sh[nd][2][lane]=nf.z; sh[nd][3][lane]=nf.w;
  }
  __syncthreads();
  float as[4]={0,0,0,0}, a0[4]={0,0,0,0}, a1[4]={0,0,0,0}, a2[4]={0,0,0,0};
  for(int f=0; f<64; ++f){
    float ws = W_in_s[f*64+lane], wv = W_in_v[f*64+lane];
    #pragma unroll
    for(int k=0;k<4;++k){
      int nd = wave*4 + k;
      as[k] = fmaf(sh[nd][0][f], ws, as[k]);
      a0[k] = fmaf(sh[nd][1][f], wv, a0[k]);
      a1[k] = fmaf(sh[nd][2][f], wv, a1[k]);
      a2[k] = fmaf(sh[nd][3][f], wv, a2[k]);
    }
  }
  #pragma unroll
  for(int k=0;k<4;++k){
    float4 o4; o4.x = as[k]*0.125f; o4.y = a0[k]*0.125f;
    o4.z = a1[k]*0.125f; o4.w = a2[k]*0.125f;
    *(float4*)(h + (size_t)((nb+k)*64 + lane)*4) = o4;
  }
}

// ---------------- edge kernel: 64 edges/block, w2 staged in LDS chunks ----------------
// agg layout: agg[node*256 + c*64 + lane]  (channel-planar: contiguous atomics)
__global__ __launch_bounds__(256) void k_edge(
    const float* __restrict__ rec,
    const float* __restrict__ mlp_w1, const float* __restrict__ mlp_w2,
    const float* __restrict__ h, float* __restrict__ agg)
{
  __shared__ float recS[4][256];       // 16 edges x 16 floats per wave (wave-local)
  __shared__ float hid[4][64][20];     // [hh][t], stride 20 (wave-local)
  __shared__ float w2S[16*320];        // one 16-hh chunk of mlp_w2 (block-shared)
  int tid = threadIdx.x;
  int wave = tid >> 6, lane = tid & 63;
  int e0 = (blockIdx.x*4 + wave)*TB;

  // stage records: 1 KB per wave in one dwordx4 (wave-local LDS, lockstep-safe)
  *(float4*)&recS[wave][lane*4] = *(const float4*)(rec + (size_t)e0*16 + lane*4);

  float wl[8];
  #pragma unroll
  for(int r=0;r<8;++r) wl[r] = mlp_w1[r*64+lane];

  // hidden = silu(rad @ w1), lane = hidden unit; store transposed [hh][t]
  #pragma unroll
  for(int t=0;t<TB;++t){
    float acc = 0.f;
    #pragma unroll
    for(int r=0;r<8;++r) acc = fmaf(recS[wave][t*16+4+r], wl[r], acc);
    hid[wave][lane][t] = acc / (1.f + __expf(-acc));
  }

  // w[j][t-pair] accumulators, packed fp32; w2 consumed from LDS chunks
  v2f wv[5][8];
  #pragma unroll
  for(int j=0;j<5;++j)
    #pragma unroll
    for(int tp=0;tp<8;++tp) wv[j][tp] = (v2f){0.f, 0.f};

  for(int c=0;c<4;++c){
    __syncthreads();                         // protect w2S from prior chunk's readers
    const float* src = mlp_w2 + c*16*320;
    #pragma unroll
    for(int k=0;k<5;++k){
      int f4 = tid + k*256;                  // 1280 float4 = 5120 floats
      *(float4*)&w2S[f4*4] = *(const float4*)(src + (size_t)f4*4);
    }
    __syncthreads();
    #pragma unroll
    for(int hl=0; hl<16; hl+=2){
      int hh = c*16 + hl;
      float b0[5], b1[5];
      #pragma unroll
      for(int j=0;j<5;++j){
        b0[j] = w2S[hl*320     + j*64 + lane];
        b1[j] = w2S[(hl+1)*320 + j*64 + lane];
      }
      #pragma unroll
      for(int tp=0;tp<8;++tp){
        v2f h0 = *(const v2f*)&hid[wave][hh][2*tp];
        v2f h1 = *(const v2f*)&hid[wave][hh+1][2*tp];
        #pragma unroll
        for(int j=0;j<5;++j){
          v2f bb0 = {b0[j], b0[j]};
          v2f bb1 = {b1[j], b1[j]};
          wv[j][tp] = PKFMA(bb0, h0, wv[j][tp]);
          wv[j][tp] = PKFMA(bb1, h1, wv[j][tp]);
        }
      }
    }
  }

  // message build + register-run accumulation; h gathered as one float4, 4-deep pipeline
  float4 hv4[4];
  #pragma unroll
  for(int p=0;p<4;++p){
    int snd = __float_as_int(recS[wave][p*16+3]);
    hv4[p] = *(const float4*)(h + (size_t)(snd*64 + lane)*4);
  }

  float as_=0.f, av0=0.f, av1=0.f, av2=0.f;
  int cur = __float_as_int(recS[wave][12]);
  #pragma unroll
  for(int t=0;t<TB;++t){
    float4 hc = hv4[t&3];
    if(t+4 < TB){
      int snd = __float_as_int(recS[wave][(t+4)*16+3]);
      hv4[t&3] = *(const float4*)(h + (size_t)(snd*64 + lane)*4);
    }
    int rcv = __float_as_int(recS[wave][t*16+12]);
    if(rcv != cur){
      size_t ro = (size_t)cur*256 + lane;
      atomicAdd(&agg[ro],     as_);
      atomicAdd(&agg[ro+64],  av0);
      atomicAdd(&agg[ro+128], av1);
      atomicAdd(&agg[ro+192], av2);
      as_=0.f; av0=0.f; av1=0.f; av2=0.f;
      cur = rcv;
    }
    float y0=recS[wave][t*16], y1=recS[wave][t*16+1], y2=recS[wave][t*16+2];
    float ss=hc.x, sv0=hc.y, sv1=hc.z, sv2=hc.w;
    float dot = sv0*y0 + sv1*y1 + sv2*y2;
    float wt0 = wv[0][t>>1][t&1], wt1 = wv[1][t>>1][t&1];
    float wt2 = wv[2][t>>1][t&1], wt3 = wv[3][t>>1][t&1], wt4 = wv[4][t>>1][t&1];
    as_ += wt0*ss + wt1*dot;
    float w2s = wt2*ss;
    av0 += w2s*y0 + wt3*sv0 + wt4*(sv1*y2 - sv2*y1);
    av1 += w2s*y1 + wt3*sv1 + wt4*(sv2*y0 - sv0*y2);
    av2 += w2s*y2 + wt3*sv2 + wt4*(sv0*y1 - sv1*y0);
  }
  size_t ro = (size_t)cur*256 + lane;
  atomicAdd(&agg[ro],     as_);
  atomicAdd(&agg[ro+64],  av0);
  atomicAdd(&agg[ro+128], av1);
  atomicAdd(&agg[ro+192], av2);
}

// ---------------- node post-pass: 4 nodes per wave ----------------
__global__ __launch_bounds__(256) void k_node_post(
  const float* __restrict__ node_feats, const int* __restrict__ specie,
  const float* __restrict__ agg,
  const float* __restrict__ Wrst, const float* __restrict__ Wrvt,
  const float* __restrict__ W_out_s, const float* __restrict__ W_out_v,
  const float* __restrict__ W_prod_s, const float* __restrict__ W_prod_v,
  const float* __restrict__ W_lin_s, const float* __restrict__ W_lin_v,
  const float* __restrict__ W_read, float* __restrict__ out_node,
  float* __restrict__ out_feats)
{
  __shared__ float shA[16][4][64];
  __shared__ float shS[16][4][64];   // node_feats first, reused for p_s/p_v
  int wave = threadIdx.x >> 6, lane = threadIdx.x & 63;
  int nb = blockIdx.x*16 + wave*4;
  #pragma unroll
  for(int k=0;k<4;++k){
    int nd = wave*4 + k;
    size_t o = (size_t)(nb+k)*256 + lane;
    shA[nd][0][lane] = agg[o]      * (1.f/16.f);
    shA[nd][1][lane] = agg[o+64]   * (1.f/16.f);
    shA[nd][2][lane] = agg[o+128]  * (1.f/16.f);
    shA[nd][3][lane] = agg[o+192]  * (1.f/16.f);
    float4 nf = *(const float4*)(node_feats + (size_t)((nb+k)*64 + lane)*4);
    shS[nd][0][lane]=nf.x; shS[nd][1][lane]=nf.y; shS[nd][2][lane]=nf.z; shS[nd][3][lane]=nf.w;
  }
  int spec[4];
  #pragma unroll
  for(int k=0;k<4;++k) spec[k] = specie[nb+k];
  __syncthreads();
  float a_s[4]={0,0,0,0}, a0[4]={0,0,0,0}, a1[4]={0,0,0,0}, a2[4]={0,0,0,0};
  float r_s[4]={0,0,0,0}, r0[4]={0,0,0,0}, r1[4]={0,0,0,0}, r2[4]={0,0,0,0};
  for(int f=0; f<64; ++f){
    float wos = W_out_s[f*64+lane], wov = W_out_v[f*64+lane];
    #pragma unroll
    for(int k=0;k<4;++k){
      int nd = wave*4 + k;
      a_s[k] = fmaf(shA[nd][0][f], wos, a_s[k]);
      a0[k]  = fmaf(shA[nd][1][f], wov, a0[k]);
      a1[k]  = fmaf(shA[nd][2][f], wov, a1[k]);
      a2[k]  = fmaf(shA[nd][3][f], wov, a2[k]);
    }
    #pragma unroll
    for(int k=0;k<4;++k){
      int nd = wave*4 + k;
      float wrs = Wrst[spec[k]*4096 + f*64 + lane];
      float wrv = Wrvt[spec[k]*4096 + f*64 + lane];
      r_s[k] = fmaf(shS[nd][0][f], wrs, r_s[k]);
      r0[k]  = fmaf(shS[nd][1][f], wrv, r0[k]);
      r1[k]  = fmaf(shS[nd][2][f], wrv, r1[k]);
      r2[k]  = fmaf(shS[nd][3][f], wrv, r2[k]);
    }
  }
  __syncthreads();
  #pragma unroll
  for(int k=0;k<4;++k){
    int nd = wave*4 + k;
    float A_s = a_s[k]*0.125f, A0 = a0[k]*0.125f, A1 = a1[k]*0.125f, A2 = a2[k]*0.125f;
    float vv = A0*A0 + A1*A1 + A2*A2;
    float as2 = A_s*A_s;
    const float* Wp = W_prod_s + spec[k]*320;
    float p_s = Wp[lane]*A_s + Wp[64+lane]*as2 + Wp[128+lane]*as2*A_s
              + Wp[192+lane]*vv + Wp[256+lane]*A_s*vv;
    const float* Wq = W_prod_v + spec[k]*256;
    float coef = Wq[lane] + Wq[64+lane]*A_s + Wq[128+lane]*as2 + Wq[192+lane]*vv;
    shS[nd][0][lane] = p_s;
    shS[nd][1][lane] = coef*A0;
    shS[nd][2][lane] = coef*A1;
    shS[nd][3][lane] = coef*A2;
  }
  __syncthreads();
  float lfs[4]={0,0,0,0}, lf0[4]={0,0,0,0}, lf1[4]={0,0,0,0}, lf2[4]={0,0,0,0};
  for(int f=0; f<64; ++f){
    float wls = W_lin_s[f*64+lane], wlv = W_lin_v[f*64+lane];
    #pragma unroll
    for(int k=0;k<4;++k){
      int nd = wave*4 + k;
      lfs[k] = fmaf(shS[nd][0][f], wls, lfs[k]);
      lf0[k] = fmaf(shS[nd][1][f], wlv, lf0[k]);
      lf1[k] = fmaf(shS[nd][2][f], wlv, lf1[k]);
      lf2[k] = fmaf(shS[nd][3][f], wlv, lf2[k]);
    }
  }
  float wr = W_read[lane];
  #pragma unroll
  for(int k=0;k<4;++k){
    int n = nb + k;
    float FS = lfs[k]*0.125f + r_s[k]*0.125f;
    float F0 = lf0[k]*0.125f + r0[k]*0.125f;
    float F1 = lf1[k]*0.125f + r1[k]*0.125f;
    float F2 = lf2[k]*0.125f + r2[k]*0.125f;
    float x = FS * wr;
    #pragma unroll
    for(int off=32; off; off>>=1) x += __shfl_down(x, off);
    if(lane==0) out_node[n] = x*0.125f;
    float4 o4; o4.x=FS; o4.y=F0; o4.z=F1; o4.w=F2;
    *(float4*)(out_feats + (size_t)(n*64+lane)*4) = o4;
  }
}

extern "C" void kernel_launch(void* const* d_in, const int* in_sizes, int n_in,
                              void* d_out, int out_size, void* d_ws, size_t ws_size,
                              hipStream_t stream) {
  const float* vectors    = (const float*)d_in[0];
  const float* node_feats = (const float*)d_in[1];
  const int*   node_specie= (const int*)  d_in[2];
  const float* radial     = (const float*)d_in[3];
  const int*   senders    = (const int*)  d_in[4];
  const int*   receivers  = (const int*)  d_in[5];
  const float* W_res_s    = (const float*)d_in[6];
  const float* W_res_v    = (const float*)d_in[7];
  const float* W_in_s     = (const float*)d_in[8];
  const float* W_in_v     = (const float*)d_in[9];
  const float* mlp_w1     = (const float*)d_in[10];
  const float* mlp_w2     = (const float*)d_in[11];
  const float* W_out_s    = (const float*)d_in[12];
  const float* W_out_v    = (const float*)d_in[13];
  const float* W_prod_s   = (const float*)d_in[14];
  const float* W_prod_v   = (const float*)d_in[15];
  const float* W_lin_s    = (const float*)d_in[16];
  const float* W_lin_v    = (const float*)d_in[17];
  const float* W_read     = (const float*)d_in[18];

  float* ws   = (float*)d_ws;
  float* h    = ws;                          // 4*NF floats, [(n*64+lane)*4+c]
  float* agg  = ws + 4*(size_t)NF;           // 4*NF floats, [n*256 + c*64 + lane]
  float* Wrst = ws + 8*(size_t)NF;           // 40960
  float* Wrvt = Wrst + 40960;                // 40960
  float* rec  = Wrvt + 40960;                // 16*NE floats (64 B per edge)
  int*   rank   = (int*)(rec + 16*(size_t)NE); // NE
  int*   offset = rank + NE;                 // NN+1
  int*   count  = offset + NN + 1;           // NN

  hipMemsetAsync(agg,   0, (size_t)4*NF*sizeof(float), stream);
  hipMemsetAsync(count, 0, (size_t)NN*sizeof(int), stream);
  k_hist_prep<<<NE/256, 256, 0, stream>>>(receivers, count, rank,
                                          W_res_s, W_res_v, Wrst, Wrvt);
  k_scan     <<<1,     1024, 0, stream>>>(count, offset);
  k_scatter  <<<NE/256, 256, 0, stream>>>(senders, receivers, vectors, radial,
                                          offset, rank, rec);
  k_node_pre<<<NN/16, 256, 0, stream>>>(node_feats, W_in_s, W_in_v, h);
  k_edge<<<NE/64, 256, 0, stream>>>(rec, mlp_w1, mlp_w2, h, agg);
  k_node_post<<<NN/16, 256, 0, stream>>>(node_feats, node_specie, agg,
                                         Wrst, Wrvt, W_out_s, W_out_v,
                                         W_prod_s, W_prod_v, W_lin_s, W_lin_v,
                                         W_read, (float*)d_out, (float*)d_out + NN);
}